// Round 7
// baseline (289.986 us; speedup 1.0000x reference)
//
#include <hip/hip_runtime.h>
#include <stdint.h>

#define B_N  4096
#define P_N  19000
#define D_N  4000
#define T_N  32
#define H1_N 2048
#define H2_N 1024

typedef __bf16 bf16x8 __attribute__((ext_vector_type(8)));
typedef float  f32x4  __attribute__((ext_vector_type(4)));

__device__ __forceinline__ unsigned short f2bf(float f) {
  union { float f; uint32_t u; } v; v.f = f;
  uint32_t u = v.u;
  uint32_t r = (u + 0x7fffu + ((u >> 16) & 1u)) >> 16;  // RNE
  return (unsigned short)r;
}

__device__ __forceinline__ float bflo(uint32_t u) {  // low bf16 of a packed u32
  union { uint32_t u; float f; } v; v.u = u << 16; return v.f;
}
__device__ __forceinline__ float bfhi(uint32_t u) {  // high bf16
  union { uint32_t u; float f; } v; v.u = u & 0xffff0000u; return v.f;
}

__device__ __forceinline__ void gload16(const void* g, void* l) {
  __builtin_amdgcn_global_load_lds((const __attribute__((address_space(1))) void*)g,
                                   (__attribute__((address_space(3))) void*)l,
                                   16, 0, 0);
}

// K0 fused prep:
//   blocks [0,19000): build W1i — pair-interleaved bf16 of W1 target rows.
//     W1i row t = 256 chunks of 32B: [blockA row t elems 8j..8j+7 | blockB row
//     (19001+t) elems 8j..8j+7]  → dsum reads one contiguous 32B per (d,t,thread).
//   blocks [19000,21048): W2 [K][N] f32 -> W2T [N][K] bf16.
//   block 21048: used-drug flags.
__global__ __launch_bounds__(256) void k_prep(const float* __restrict__ W1,
                                              unsigned short* __restrict__ W1i,
                                              const float* __restrict__ W2,
                                              unsigned short* __restrict__ W2T,
                                              const int* __restrict__ dp,
                                              unsigned char* __restrict__ flags) {
  __shared__ float tile[32][33];
  const int b = blockIdx.x;
  if (b < 19000) {
    const int tid = threadIdx.x;
    const float4* pa = (const float4*)(W1 + (size_t)b * H1_N + tid * 8);
    const float4* pb = (const float4*)(W1 + (size_t)(19001 + b) * H1_N + tid * 8);
    float4 a0 = pa[0], a1 = pa[1], b0 = pb[0], b1 = pb[1];
    unsigned short ra[8] = { f2bf(a0.x), f2bf(a0.y), f2bf(a0.z), f2bf(a0.w),
                             f2bf(a1.x), f2bf(a1.y), f2bf(a1.z), f2bf(a1.w) };
    unsigned short rb[8] = { f2bf(b0.x), f2bf(b0.y), f2bf(b0.z), f2bf(b0.w),
                             f2bf(b1.x), f2bf(b1.y), f2bf(b1.z), f2bf(b1.w) };
    unsigned short* dst = W1i + (size_t)b * 4096 + tid * 16;
    *(uint4*)(dst)     = *(uint4*)ra;
    *(uint4*)(dst + 8) = *(uint4*)rb;
  } else if (b < 19000 + 2048) {
    const int bb = b - 19000;
    const int bx = bb & 31;   // n-tile (1024/32)
    const int by = bb >> 5;   // k-tile (2048/32)
    const int tx = threadIdx.x & 31, ty = threadIdx.x >> 5;
    #pragma unroll
    for (int i = 0; i < 4; ++i)
      tile[ty + i*8][tx] = W2[(size_t)(by*32 + ty + i*8) * H2_N + bx*32 + tx];
    __syncthreads();
    #pragma unroll
    for (int i = 0; i < 4; ++i) {
      const int n = bx*32 + ty + i*8;
      const int k = by*32 + tx;
      W2T[(size_t)n * H1_N + k] = f2bf(tile[tx][ty + i*8]);
    }
  } else {
    const int tid = threadIdx.x;
    for (int i = tid; i < D_N; i += 256) flags[i] = 0;
    __syncthreads();
    for (int i = tid; i < 2 * B_N; i += 256) flags[dp[i]] = 1;
  }
}

// K1: per-drug sums over pair-interleaved W1i (dup targets weighted 0; unused
// drugs skipped). One contiguous 32B read per (target, thread). f32 accum, bf16 out.
__global__ __launch_bounds__(256) void k_dsum(const int* __restrict__ dt,
                                              const unsigned char* __restrict__ flags,
                                              const unsigned short* __restrict__ W1i,
                                              unsigned short* __restrict__ SAb,
                                              unsigned short* __restrict__ SBb) {
  const int d = blockIdx.x;
  if (!flags[d]) return;                      // block-uniform early exit
  __shared__ int   tgt[T_N];
  __shared__ float wgt[T_N];
  const int tid = threadIdx.x;
  if (tid < T_N) tgt[tid] = dt[d * T_N + tid];
  __syncthreads();
  if (tid < T_N) {
    int v = 1, t = tgt[tid];
    for (int j = 0; j < tid; ++j) v &= (tgt[j] != t);
    wgt[tid] = (float)v;
  }
  __syncthreads();
  float aA[8] = {0,0,0,0,0,0,0,0};
  float aB[8] = {0,0,0,0,0,0,0,0};
  #pragma unroll 4
  for (int t = 0; t < T_N; ++t) {
    const float w = wgt[t];
    const uint4* pp = (const uint4*)(W1i + (size_t)tgt[t] * 4096 + tid * 16);
    uint4 a = pp[0];
    uint4 b = pp[1];
    uint32_t au[4] = {a.x, a.y, a.z, a.w};
    uint32_t bu[4] = {b.x, b.y, b.z, b.w};
    #pragma unroll
    for (int k = 0; k < 4; ++k) {
      aA[2*k]   = fmaf(w, bflo(au[k]), aA[2*k]);
      aA[2*k+1] = fmaf(w, bfhi(au[k]), aA[2*k+1]);
      aB[2*k]   = fmaf(w, bflo(bu[k]), aB[2*k]);
      aB[2*k+1] = fmaf(w, bfhi(bu[k]), aB[2*k+1]);
    }
  }
  unsigned short oa[8], ob[8];
  #pragma unroll
  for (int k = 0; k < 8; ++k) { oa[k] = f2bf(aA[k]); ob[k] = f2bf(aB[k]); }
  const int c0 = tid * 8;
  *(uint4*)(SAb + (size_t)d * H1_N + c0) = *(uint4*)oa;
  *(uint4*)(SBb + (size_t)d * H1_N + c0) = *(uint4*)ob;
}

// K2: h1[r,:] = relu(S_A[dA] + S_B[dB] + cA*W1[P] + cB*W1[2P+1] + b1), bf16 out.
// Rows [0,B): order_1 (dA=drug0). Rows [B,2B): order_2 (dA=drug1).
__global__ __launch_bounds__(256) void k_h1(const int* __restrict__ dp, const float* __restrict__ conc,
                                            const float* __restrict__ W1, const float* __restrict__ b1,
                                            const unsigned short* __restrict__ SAb,
                                            const unsigned short* __restrict__ SBb,
                                            unsigned short* __restrict__ h1) {
  const int rI   = blockIdx.x;
  const int swap = (rI >= B_N) ? 1 : 0;
  const int rr   = swap ? rI - B_N : rI;
  const int dA = dp[2*rr + swap];
  const int dB = dp[2*rr + (1 - swap)];
  const float cA = conc[2*rr + swap];
  const float cB = conc[2*rr + (1 - swap)];
  const int c0 = threadIdx.x * 8;
  uint4 ua = *(const uint4*)(SAb + (size_t)dA * H1_N + c0);
  uint4 ub = *(const uint4*)(SBb + (size_t)dB * H1_N + c0);
  uint32_t au[4] = {ua.x, ua.y, ua.z, ua.w};
  uint32_t bu[4] = {ub.x, ub.y, ub.z, ub.w};
  const float4* wp = (const float4*)(W1 + (size_t)P_N * H1_N + c0);
  const float4* wq = (const float4*)(W1 + (size_t)(2*P_N + 1) * H1_N + c0);
  const float4* bp = (const float4*)(b1 + c0);
  float a[8], b[8], p[8], q[8], z[8];
  #pragma unroll
  for (int k = 0; k < 4; ++k) {
    a[2*k] = bflo(au[k]); a[2*k+1] = bfhi(au[k]);
    b[2*k] = bflo(bu[k]); b[2*k+1] = bfhi(bu[k]);
  }
  float4 p0 = wp[0], p1 = wp[1], q0 = wq[0], q1 = wq[1], z0 = bp[0], z1 = bp[1];
  p[0]=p0.x;p[1]=p0.y;p[2]=p0.z;p[3]=p0.w;p[4]=p1.x;p[5]=p1.y;p[6]=p1.z;p[7]=p1.w;
  q[0]=q0.x;q[1]=q0.y;q[2]=q0.z;q[3]=q0.w;q[4]=q1.x;q[5]=q1.y;q[6]=q1.z;q[7]=q1.w;
  z[0]=z0.x;z[1]=z0.y;z[2]=z0.z;z[3]=z0.w;z[4]=z1.x;z[5]=z1.y;z[6]=z1.z;z[7]=z1.w;
  unsigned short res[8];
  #pragma unroll
  for (int k = 0; k < 8; ++k)
    res[k] = f2bf(fmaxf(a[k] + b[k] + cA*p[k] + cB*q[k] + z[k], 0.f));
  *(uint4*)(h1 + (size_t)rI * H1_N + c0) = *(uint4*)res;
}

// K3: fused h2 = relu(h1 @ W2 + b2), out-partial = sum_col relu(h2)*W3[col].
// BM=64, BN=256, FULL K=2048 (ReLU forbids K-splitting). T3-min double-buffer:
// stage tile t+1 into buf^1 BEFORE computing tile t; ONE __syncthreads per
// K-step (compiler's pre-barrier vmcnt(0)/lgkmcnt(0) drain provides the
// ordering: stage lands before next read; ds_reads retired before overwrite).
// LDS = 2*(8KB A + 32KB B) = 80KB -> 2 blocks/CU. Epilogue ps aliases As.
__global__ __launch_bounds__(256, 2) void k_gemm(const unsigned short* __restrict__ A,
                                                 const unsigned short* __restrict__ Bm,
                                                 const float* __restrict__ b2,
                                                 const float* __restrict__ W3,
                                                 float* __restrict__ partial) {
  __shared__ unsigned short As[2][64 * 64];
  __shared__ unsigned short Bs[2][256 * 64];
  const int tid  = threadIdx.x;
  const int wv   = tid >> 6;
  const int lane = tid & 63;
  const int bid  = blockIdx.x;
  const int m0 = (bid >> 2) * 64;
  const int nq = bid & 3;                   // n-quarter (256 cols)
  const int n0 = nq * 256;
  const int wn = wv * 64;
  const int r = lane & 15;
  const int g = lane >> 4;
  const int srow = lane >> 3;               // row within 8-row chunk
  const int slot = (lane & 7) ^ srow;       // logical 16B slot this lane fetches

  f32x4 acc[4][4] = {};

  // prologue: stage K-tile 0 into buffer 0
  {
    const int k0 = 0;
    #pragma unroll
    for (int i = 0; i < 2; ++i) {
      const int c   = i * 4 + wv;
      const int row = c * 8 + srow;
      gload16(A + (size_t)(m0 + row) * H1_N + k0 + slot * 8, (char*)As[0] + c * 1024);
    }
    #pragma unroll
    for (int i = 0; i < 8; ++i) {
      const int c   = i * 4 + wv;
      const int row = c * 8 + srow;
      gload16(Bm + (size_t)(n0 + row) * H1_N + k0 + slot * 8, (char*)Bs[0] + c * 1024);
    }
  }
  __syncthreads();

  for (int kt = 0; kt < 32; ++kt) {
    const int cb = kt & 1;
    if (kt < 31) {                           // stage next tile into buf^1
      const int k0 = (kt + 1) * 64;
      const int nb = cb ^ 1;
      #pragma unroll
      for (int i = 0; i < 2; ++i) {
        const int c   = i * 4 + wv;
        const int row = c * 8 + srow;
        gload16(A + (size_t)(m0 + row) * H1_N + k0 + slot * 8, (char*)As[nb] + c * 1024);
      }
      #pragma unroll
      for (int i = 0; i < 8; ++i) {
        const int c   = i * 4 + wv;
        const int row = c * 8 + srow;
        gload16(Bm + (size_t)(n0 + row) * H1_N + k0 + slot * 8, (char*)Bs[nb] + c * 1024);
      }
    }
    #pragma unroll
    for (int kk = 0; kk < 2; ++kk) {
      bf16x8 af[4], bfr[4];
      #pragma unroll
      for (int mi = 0; mi < 4; ++mi) {
        const int row = mi * 16 + r;
        const int s   = (kk * 4 + g) ^ (row & 7);
        af[mi] = *(const bf16x8*)((const char*)As[cb] + row * 128 + s * 16);
      }
      #pragma unroll
      for (int ni = 0; ni < 4; ++ni) {
        const int col = wn + ni * 16 + r;
        const int s   = (kk * 4 + g) ^ (col & 7);
        bfr[ni] = *(const bf16x8*)((const char*)Bs[cb] + col * 128 + s * 16);
      }
      #pragma unroll
      for (int mi = 0; mi < 4; ++mi)
        #pragma unroll
        for (int ni = 0; ni < 4; ++ni)
          acc[mi][ni] = __builtin_amdgcn_mfma_f32_16x16x32_bf16(af[mi], bfr[ni], acc[mi][ni], 0, 0, 0);
    }
    __syncthreads();   // drains vmcnt(0)+lgkmcnt(0): stage landed, reads retired
  }
  // Epilogue: C/D layout col=lane&15 (r), row=g*4+q within fragment.
  // relu+dot with W3 per lane's 4 cols, shfl-reduce the 16-lane col group,
  // then sum the 4 waves' rowsums via LDS (ps aliases As — dead after loop).
  float* ps = (float*)As;                    // [4][64]
  float b2v[4], w3v[4];
  #pragma unroll
  for (int ni = 0; ni < 4; ++ni) {
    const int col = n0 + wn + ni * 16 + r;
    b2v[ni] = b2[col];
    w3v[ni] = W3[col];
  }
  float rs[16];
  #pragma unroll
  for (int mi = 0; mi < 4; ++mi)
    #pragma unroll
    for (int q = 0; q < 4; ++q) {
      float s = 0.f;
      #pragma unroll
      for (int ni = 0; ni < 4; ++ni)
        s += fmaxf(acc[mi][ni][q] + b2v[ni], 0.f) * w3v[ni];
      rs[mi*4+q] = s;
    }
  #pragma unroll
  for (int o = 1; o < 16; o <<= 1)
    #pragma unroll
    for (int k = 0; k < 16; ++k)
      rs[k] += __shfl_xor(rs[k], o, 64);
  if (r == 0)
    #pragma unroll
    for (int mi = 0; mi < 4; ++mi)
      #pragma unroll
      for (int q = 0; q < 4; ++q)
        ps[wv * 64 + mi*16 + g*4 + q] = rs[mi*4+q];
  __syncthreads();
  if (tid < 64)
    partial[(size_t)nq * (2*B_N) + m0 + tid] =
        ps[0*64 + tid] + ps[1*64 + tid] + ps[2*64 + tid] + ps[3*64 + tid];
}

// K4: out[i] = sum_j partial[j][i] + b3
__global__ __launch_bounds__(256) void k_fin(const float* __restrict__ partial,
                                             const float* __restrict__ b3,
                                             float* __restrict__ out) {
  const int i = blockIdx.x * 256 + threadIdx.x;
  float s = b3[0];
  #pragma unroll
  for (int j = 0; j < 4; ++j) s += partial[(size_t)j * (2*B_N) + i];
  out[i] = s;
}

extern "C" void kernel_launch(void* const* d_in, const int* in_sizes, int n_in,
                              void* d_out, int out_size, void* d_ws, size_t ws_size,
                              hipStream_t stream) {
  const int*   dp   = (const int*)d_in[0];
  const int*   dt   = (const int*)d_in[1];
  const float* conc = (const float*)d_in[2];
  const float* W1   = (const float*)d_in[3];
  const float* b1   = (const float*)d_in[4];
  const float* W2   = (const float*)d_in[5];
  const float* b2   = (const float*)d_in[6];
  const float* W3   = (const float*)d_in[7];
  const float* b3   = (const float*)d_in[8];
  float* out = (float*)d_out;

  // ws layout (bytes) — W1i = 19000*4096*2 = 155,648,000 B:
  //   [0,         155648000)  W1i bf16 pair-interleaved  (dead after k_dsum)
  //      aliased after k_dsum by:
  //        h1       bf16 [8192][2048] at 0 .. 33554432
  //        partials f32  [4][8192]    at 33554432 .. 33685504
  //   [155656192, 172040192)  SAb bf16 [4000][2048]   (16,384,000 B)
  //   [172040192, 188424192)  SBb bf16 [4000][2048]
  //   [188424192, 192618496)  w2t bf16 [1024][2048]
  //   [192618496, 192622496)  flags u8 [4000]          (total ~192.6 MB)
  char* ws = (char*)d_ws;
  unsigned short* W1i   = (unsigned short*)ws;
  unsigned short* h1    = (unsigned short*)ws;
  float*          parts = (float*)(ws + 33554432);
  unsigned short* SAb   = (unsigned short*)(ws + 155656192);
  unsigned short* SBb   = (unsigned short*)(ws + 172040192);
  unsigned short* w2t   = (unsigned short*)(ws + 188424192);
  unsigned char*  flags = (unsigned char*)(ws + 192618496);

  k_prep<<<21049,  256, 0, stream>>>(W1, W1i, W2, w2t, dp, flags);
  k_dsum<<<D_N,    256, 0, stream>>>(dt, flags, W1i, SAb, SBb);
  k_h1  <<<2*B_N,  256, 0, stream>>>(dp, conc, W1, b1, SAb, SBb, h1);
  k_gemm<<<512,    256, 0, stream>>>(h1, w2t, b2, W3, parts);
  k_fin <<<32,     256, 0, stream>>>(parts, b3, out);
}

// Round 8
// 275.625 us; speedup vs baseline: 1.0521x; 1.0521x over previous
//
#include <hip/hip_runtime.h>
#include <stdint.h>

#define B_N  4096
#define P_N  19000
#define D_N  4000
#define T_N  32
#define H1_N 2048
#define H2_N 1024

typedef __bf16 bf16x8 __attribute__((ext_vector_type(8)));
typedef float  f32x4  __attribute__((ext_vector_type(4)));

__device__ __forceinline__ unsigned short f2bf(float f) {
  union { float f; uint32_t u; } v; v.f = f;
  uint32_t u = v.u;
  uint32_t r = (u + 0x7fffu + ((u >> 16) & 1u)) >> 16;  // RNE
  return (unsigned short)r;
}

__device__ __forceinline__ float bflo(uint32_t u) {  // low bf16 of a packed u32
  union { uint32_t u; float f; } v; v.u = u << 16; return v.f;
}
__device__ __forceinline__ float bfhi(uint32_t u) {  // high bf16
  union { uint32_t u; float f; } v; v.u = u & 0xffff0000u; return v.f;
}

__device__ __forceinline__ void gload16(const void* g, void* l) {
  __builtin_amdgcn_global_load_lds((const __attribute__((address_space(1))) void*)g,
                                   (__attribute__((address_space(3))) void*)l,
                                   16, 0, 0);
}

// K0 fused prep:
//   blocks [0,19000): build W1i — pair-interleaved bf16 of W1 target rows.
//     W1i row t = 256 chunks of 32B: [blockA row t elems 8j..8j+7 | blockB row
//     (19001+t) elems 8j..8j+7]  → dsum reads one contiguous 32B per (d,t,thread).
//   blocks [19000,21048): W2 [K][N] f32 -> W2T [N][K] bf16.
//   block 21048: used-drug flags.
__global__ __launch_bounds__(256) void k_prep(const float* __restrict__ W1,
                                              unsigned short* __restrict__ W1i,
                                              const float* __restrict__ W2,
                                              unsigned short* __restrict__ W2T,
                                              const int* __restrict__ dp,
                                              unsigned char* __restrict__ flags) {
  __shared__ float tile[32][33];
  const int b = blockIdx.x;
  if (b < 19000) {
    const int tid = threadIdx.x;
    const float4* pa = (const float4*)(W1 + (size_t)b * H1_N + tid * 8);
    const float4* pb = (const float4*)(W1 + (size_t)(19001 + b) * H1_N + tid * 8);
    float4 a0 = pa[0], a1 = pa[1], b0 = pb[0], b1 = pb[1];
    unsigned short ra[8] = { f2bf(a0.x), f2bf(a0.y), f2bf(a0.z), f2bf(a0.w),
                             f2bf(a1.x), f2bf(a1.y), f2bf(a1.z), f2bf(a1.w) };
    unsigned short rb[8] = { f2bf(b0.x), f2bf(b0.y), f2bf(b0.z), f2bf(b0.w),
                             f2bf(b1.x), f2bf(b1.y), f2bf(b1.z), f2bf(b1.w) };
    unsigned short* dst = W1i + (size_t)b * 4096 + tid * 16;
    *(uint4*)(dst)     = *(uint4*)ra;
    *(uint4*)(dst + 8) = *(uint4*)rb;
  } else if (b < 19000 + 2048) {
    const int bb = b - 19000;
    const int bx = bb & 31;   // n-tile (1024/32)
    const int by = bb >> 5;   // k-tile (2048/32)
    const int tx = threadIdx.x & 31, ty = threadIdx.x >> 5;
    #pragma unroll
    for (int i = 0; i < 4; ++i)
      tile[ty + i*8][tx] = W2[(size_t)(by*32 + ty + i*8) * H2_N + bx*32 + tx];
    __syncthreads();
    #pragma unroll
    for (int i = 0; i < 4; ++i) {
      const int n = bx*32 + ty + i*8;
      const int k = by*32 + tx;
      W2T[(size_t)n * H1_N + k] = f2bf(tile[tx][ty + i*8]);
    }
  } else {
    const int tid = threadIdx.x;
    for (int i = tid; i < D_N; i += 256) flags[i] = 0;
    __syncthreads();
    for (int i = tid; i < 2 * B_N; i += 256) flags[dp[i]] = 1;
  }
}

// K1: per-drug sums over pair-interleaved W1i (dup targets weighted 0; unused
// drugs skipped). One contiguous 32B read per (target, thread). f32 accum, bf16 out.
__global__ __launch_bounds__(256) void k_dsum(const int* __restrict__ dt,
                                              const unsigned char* __restrict__ flags,
                                              const unsigned short* __restrict__ W1i,
                                              unsigned short* __restrict__ SAb,
                                              unsigned short* __restrict__ SBb) {
  const int d = blockIdx.x;
  if (!flags[d]) return;                      // block-uniform early exit
  __shared__ int   tgt[T_N];
  __shared__ float wgt[T_N];
  const int tid = threadIdx.x;
  if (tid < T_N) tgt[tid] = dt[d * T_N + tid];
  __syncthreads();
  if (tid < T_N) {
    int v = 1, t = tgt[tid];
    for (int j = 0; j < tid; ++j) v &= (tgt[j] != t);
    wgt[tid] = (float)v;
  }
  __syncthreads();
  float aA[8] = {0,0,0,0,0,0,0,0};
  float aB[8] = {0,0,0,0,0,0,0,0};
  #pragma unroll 4
  for (int t = 0; t < T_N; ++t) {
    const float w = wgt[t];
    const uint4* pp = (const uint4*)(W1i + (size_t)tgt[t] * 4096 + tid * 16);
    uint4 a = pp[0];
    uint4 b = pp[1];
    uint32_t au[4] = {a.x, a.y, a.z, a.w};
    uint32_t bu[4] = {b.x, b.y, b.z, b.w};
    #pragma unroll
    for (int k = 0; k < 4; ++k) {
      aA[2*k]   = fmaf(w, bflo(au[k]), aA[2*k]);
      aA[2*k+1] = fmaf(w, bfhi(au[k]), aA[2*k+1]);
      aB[2*k]   = fmaf(w, bflo(bu[k]), aB[2*k]);
      aB[2*k+1] = fmaf(w, bfhi(bu[k]), aB[2*k+1]);
    }
  }
  unsigned short oa[8], ob[8];
  #pragma unroll
  for (int k = 0; k < 8; ++k) { oa[k] = f2bf(aA[k]); ob[k] = f2bf(aB[k]); }
  const int c0 = tid * 8;
  *(uint4*)(SAb + (size_t)d * H1_N + c0) = *(uint4*)oa;
  *(uint4*)(SBb + (size_t)d * H1_N + c0) = *(uint4*)ob;
}

// K2: h1[r,:] = relu(S_A[dA] + S_B[dB] + cA*W1[P] + cB*W1[2P+1] + b1), bf16 out.
// Rows [0,B): order_1 (dA=drug0). Rows [B,2B): order_2 (dA=drug1).
__global__ __launch_bounds__(256) void k_h1(const int* __restrict__ dp, const float* __restrict__ conc,
                                            const float* __restrict__ W1, const float* __restrict__ b1,
                                            const unsigned short* __restrict__ SAb,
                                            const unsigned short* __restrict__ SBb,
                                            unsigned short* __restrict__ h1) {
  const int rI   = blockIdx.x;
  const int swap = (rI >= B_N) ? 1 : 0;
  const int rr   = swap ? rI - B_N : rI;
  const int dA = dp[2*rr + swap];
  const int dB = dp[2*rr + (1 - swap)];
  const float cA = conc[2*rr + swap];
  const float cB = conc[2*rr + (1 - swap)];
  const int c0 = threadIdx.x * 8;
  uint4 ua = *(const uint4*)(SAb + (size_t)dA * H1_N + c0);
  uint4 ub = *(const uint4*)(SBb + (size_t)dB * H1_N + c0);
  uint32_t au[4] = {ua.x, ua.y, ua.z, ua.w};
  uint32_t bu[4] = {ub.x, ub.y, ub.z, ub.w};
  const float4* wp = (const float4*)(W1 + (size_t)P_N * H1_N + c0);
  const float4* wq = (const float4*)(W1 + (size_t)(2*P_N + 1) * H1_N + c0);
  const float4* bp = (const float4*)(b1 + c0);
  float a[8], b[8], p[8], q[8], z[8];
  #pragma unroll
  for (int k = 0; k < 4; ++k) {
    a[2*k] = bflo(au[k]); a[2*k+1] = bfhi(au[k]);
    b[2*k] = bflo(bu[k]); b[2*k+1] = bfhi(bu[k]);
  }
  float4 p0 = wp[0], p1 = wp[1], q0 = wq[0], q1 = wq[1], z0 = bp[0], z1 = bp[1];
  p[0]=p0.x;p[1]=p0.y;p[2]=p0.z;p[3]=p0.w;p[4]=p1.x;p[5]=p1.y;p[6]=p1.z;p[7]=p1.w;
  q[0]=q0.x;q[1]=q0.y;q[2]=q0.z;q[3]=q0.w;q[4]=q1.x;q[5]=q1.y;q[6]=q1.z;q[7]=q1.w;
  z[0]=z0.x;z[1]=z0.y;z[2]=z0.z;z[3]=z0.w;z[4]=z1.x;z[5]=z1.y;z[6]=z1.z;z[7]=z1.w;
  unsigned short res[8];
  #pragma unroll
  for (int k = 0; k < 8; ++k)
    res[k] = f2bf(fmaxf(a[k] + b[k] + cA*p[k] + cB*q[k] + z[k], 0.f));
  *(uint4*)(h1 + (size_t)rI * H1_N + c0) = *(uint4*)res;
}

// K3: fused h2 = relu(h1 @ W2 + b2), out-partial = sum_col relu(h2)*W3[col].
// BM=64, BN=256, FULL K=2048 per block (ReLU forbids K-splitting).
// SINGLE-buffer staging, 41.5 KB LDS -> 3 blocks/CU (round-7 dbuf at 80 KB cut
// occupancy to 2/CU and regressed +22us — the m132 trap; implicit wave-level
// overlap at 3 blocks/CU beats explicit dbuf whose barrier drains vmcnt anyway).
// Both-sides XOR slot swizzle (rule 21).
__global__ __launch_bounds__(256, 2) void k_gemm(const unsigned short* __restrict__ A,
                                                 const unsigned short* __restrict__ Bm,
                                                 const float* __restrict__ b2,
                                                 const float* __restrict__ W3,
                                                 float* __restrict__ partial) {
  __shared__ unsigned short As[64 * 64];
  __shared__ unsigned short Bs[256 * 64];
  __shared__ float ps[4][64];
  const int tid  = threadIdx.x;
  const int wv   = tid >> 6;
  const int lane = tid & 63;
  const int bid  = blockIdx.x;
  const int m0 = (bid >> 2) * 64;
  const int nq = bid & 3;                   // n-quarter (256 cols)
  const int n0 = nq * 256;
  const int wn = wv * 64;
  const int r = lane & 15;
  const int g = lane >> 4;
  const int srow = lane >> 3;               // row within 8-row chunk
  const int slot = (lane & 7) ^ srow;       // logical 16B slot this lane fetches

  f32x4 acc[4][4] = {};

  for (int kt = 0; kt < 32; ++kt) {
    const int k0 = kt * 64;
    #pragma unroll
    for (int i = 0; i < 2; ++i) {           // A: 8 chunks of 1KB
      const int c   = i * 4 + wv;
      const int row = c * 8 + srow;
      gload16(A + (size_t)(m0 + row) * H1_N + k0 + slot * 8, (char*)As + c * 1024);
    }
    #pragma unroll
    for (int i = 0; i < 8; ++i) {           // B: 32 chunks of 1KB
      const int c   = i * 4 + wv;
      const int row = c * 8 + srow;
      gload16(Bm + (size_t)(n0 + row) * H1_N + k0 + slot * 8, (char*)Bs + c * 1024);
    }
    __syncthreads();                         // drains vmcnt before compute
    #pragma unroll
    for (int kk = 0; kk < 2; ++kk) {
      bf16x8 af[4], bfr[4];
      #pragma unroll
      for (int mi = 0; mi < 4; ++mi) {
        const int row = mi * 16 + r;
        const int s   = (kk * 4 + g) ^ (row & 7);
        af[mi] = *(const bf16x8*)((const char*)As + row * 128 + s * 16);
      }
      #pragma unroll
      for (int ni = 0; ni < 4; ++ni) {
        const int col = wn + ni * 16 + r;
        const int s   = (kk * 4 + g) ^ (col & 7);
        bfr[ni] = *(const bf16x8*)((const char*)Bs + col * 128 + s * 16);
      }
      #pragma unroll
      for (int mi = 0; mi < 4; ++mi)
        #pragma unroll
        for (int ni = 0; ni < 4; ++ni)
          acc[mi][ni] = __builtin_amdgcn_mfma_f32_16x16x32_bf16(af[mi], bfr[ni], acc[mi][ni], 0, 0, 0);
    }
    __syncthreads();                         // protect LDS before next stage
  }
  // Epilogue: C/D layout col=lane&15 (r), row=g*4+q within fragment.
  // Full-K pre-activations now live in acc: relu+dot with W3 per lane's 4 cols,
  // shfl-reduce the 16-lane col group, then sum the 4 waves' rowsums via LDS.
  float b2v[4], w3v[4];
  #pragma unroll
  for (int ni = 0; ni < 4; ++ni) {
    const int col = n0 + wn + ni * 16 + r;
    b2v[ni] = b2[col];
    w3v[ni] = W3[col];
  }
  float rs[16];
  #pragma unroll
  for (int mi = 0; mi < 4; ++mi)
    #pragma unroll
    for (int q = 0; q < 4; ++q) {
      float s = 0.f;
      #pragma unroll
      for (int ni = 0; ni < 4; ++ni)
        s += fmaxf(acc[mi][ni][q] + b2v[ni], 0.f) * w3v[ni];
      rs[mi*4+q] = s;
    }
  #pragma unroll
  for (int o = 1; o < 16; o <<= 1)
    #pragma unroll
    for (int k = 0; k < 16; ++k)
      rs[k] += __shfl_xor(rs[k], o, 64);
  if (r == 0)
    #pragma unroll
    for (int mi = 0; mi < 4; ++mi)
      #pragma unroll
      for (int q = 0; q < 4; ++q)
        ps[wv][mi*16 + g*4 + q] = rs[mi*4+q];
  __syncthreads();
  if (tid < 64)
    partial[(size_t)nq * (2*B_N) + m0 + tid] =
        ps[0][tid] + ps[1][tid] + ps[2][tid] + ps[3][tid];
}

// K4: out[i] = sum_j partial[j][i] + b3
__global__ __launch_bounds__(256) void k_fin(const float* __restrict__ partial,
                                             const float* __restrict__ b3,
                                             float* __restrict__ out) {
  const int i = blockIdx.x * 256 + threadIdx.x;
  float s = b3[0];
  #pragma unroll
  for (int j = 0; j < 4; ++j) s += partial[(size_t)j * (2*B_N) + i];
  out[i] = s;
}

extern "C" void kernel_launch(void* const* d_in, const int* in_sizes, int n_in,
                              void* d_out, int out_size, void* d_ws, size_t ws_size,
                              hipStream_t stream) {
  const int*   dp   = (const int*)d_in[0];
  const int*   dt   = (const int*)d_in[1];
  const float* conc = (const float*)d_in[2];
  const float* W1   = (const float*)d_in[3];
  const float* b1   = (const float*)d_in[4];
  const float* W2   = (const float*)d_in[5];
  const float* b2   = (const float*)d_in[6];
  const float* W3   = (const float*)d_in[7];
  const float* b3   = (const float*)d_in[8];
  float* out = (float*)d_out;

  // ws layout (bytes) — W1i = 19000*4096*2 = 155,648,000 B:
  //   [0,         155648000)  W1i bf16 pair-interleaved  (dead after k_dsum)
  //      aliased after k_dsum by:
  //        h1       bf16 [8192][2048] at 0 .. 33554432
  //        partials f32  [4][8192]    at 33554432 .. 33685504
  //   [155656192, 172040192)  SAb bf16 [4000][2048]   (16,384,000 B)
  //   [172040192, 188424192)  SBb bf16 [4000][2048]
  //   [188424192, 192618496)  w2t bf16 [1024][2048]
  //   [192618496, 192622496)  flags u8 [4000]          (total ~192.6 MB)
  char* ws = (char*)d_ws;
  unsigned short* W1i   = (unsigned short*)ws;
  unsigned short* h1    = (unsigned short*)ws;
  float*          parts = (float*)(ws + 33554432);
  unsigned short* SAb   = (unsigned short*)(ws + 155656192);
  unsigned short* SBb   = (unsigned short*)(ws + 172040192);
  unsigned short* w2t   = (unsigned short*)(ws + 188424192);
  unsigned char*  flags = (unsigned char*)(ws + 192618496);

  k_prep<<<21049,  256, 0, stream>>>(W1, W1i, W2, w2t, dp, flags);
  k_dsum<<<D_N,    256, 0, stream>>>(dt, flags, W1i, SAb, SBb);
  k_h1  <<<2*B_N,  256, 0, stream>>>(dp, conc, W1, b1, SAb, SBb, h1);
  k_gemm<<<512,    256, 0, stream>>>(h1, w2t, b2, W3, parts);
  k_fin <<<32,     256, 0, stream>>>(parts, b3, out);
}

// Round 9
// 270.707 us; speedup vs baseline: 1.0712x; 1.0182x over previous
//
#include <hip/hip_runtime.h>
#include <stdint.h>

#define B_N  4096
#define P_N  19000
#define D_N  4000
#define T_N  32
#define H1_N 2048
#define H2_N 1024

typedef __bf16 bf16x8 __attribute__((ext_vector_type(8)));
typedef float  f32x4  __attribute__((ext_vector_type(4)));

__device__ __forceinline__ unsigned short f2bf(float f) {
  union { float f; uint32_t u; } v; v.f = f;
  uint32_t u = v.u;
  uint32_t r = (u + 0x7fffu + ((u >> 16) & 1u)) >> 16;  // RNE
  return (unsigned short)r;
}

__device__ __forceinline__ float bflo(uint32_t u) {  // low bf16 of a packed u32
  union { uint32_t u; float f; } v; v.u = u << 16; return v.f;
}
__device__ __forceinline__ float bfhi(uint32_t u) {  // high bf16
  union { uint32_t u; float f; } v; v.u = u & 0xffff0000u; return v.f;
}

__device__ __forceinline__ void gload16(const void* g, void* l) {
  __builtin_amdgcn_global_load_lds((const __attribute__((address_space(1))) void*)g,
                                   (__attribute__((address_space(3))) void*)l,
                                   16, 0, 0);
}

// K0 fused prep: blocks [0,38002) convert W1 f32->bf16 (plain row layout —
// round-8 A/B showed the pair-interleaved W1i was ~8us WORSE than this);
// [38002,40050) transpose W2 -> bf16 [N][K]; block 40050 builds used-drug flags.
__global__ __launch_bounds__(256) void k_prep(const float* __restrict__ W1,
                                              unsigned short* __restrict__ W1b,
                                              const float* __restrict__ W2,
                                              unsigned short* __restrict__ W2T,
                                              const int* __restrict__ dp,
                                              unsigned char* __restrict__ flags) {
  __shared__ float tile[32][33];
  const int b = blockIdx.x;
  if (b < 38002) {
    const size_t base = (size_t)b * H1_N + threadIdx.x * 8;
    const float4* p = (const float4*)(W1 + base);
    float4 x = p[0], y = p[1];
    unsigned short r[8] = { f2bf(x.x), f2bf(x.y), f2bf(x.z), f2bf(x.w),
                            f2bf(y.x), f2bf(y.y), f2bf(y.z), f2bf(y.w) };
    *(uint4*)(W1b + base) = *(uint4*)r;
  } else if (b < 38002 + 2048) {
    const int bb = b - 38002;
    const int bx = bb & 31;   // n-tile (1024/32)
    const int by = bb >> 5;   // k-tile (2048/32)
    const int tx = threadIdx.x & 31, ty = threadIdx.x >> 5;
    #pragma unroll
    for (int i = 0; i < 4; ++i)
      tile[ty + i*8][tx] = W2[(size_t)(by*32 + ty + i*8) * H2_N + bx*32 + tx];
    __syncthreads();
    #pragma unroll
    for (int i = 0; i < 4; ++i) {
      const int n = bx*32 + ty + i*8;
      const int k = by*32 + tx;
      W2T[(size_t)n * H1_N + k] = f2bf(tile[tx][ty + i*8]);
    }
  } else {
    const int tid = threadIdx.x;
    for (int i = tid; i < D_N; i += 256) flags[i] = 0;
    __syncthreads();
    for (int i = tid; i < 2 * B_N; i += 256) flags[dp[i]] = 1;
  }
}

// K1: per-drug sums of bf16 W1 rows (dup targets weighted 0; unused drugs skipped).
// Accumulate f32, store bf16.
__global__ __launch_bounds__(256) void k_dsum(const int* __restrict__ dt,
                                              const unsigned char* __restrict__ flags,
                                              const unsigned short* __restrict__ W1b,
                                              unsigned short* __restrict__ SAb,
                                              unsigned short* __restrict__ SBb) {
  const int d = blockIdx.x;
  if (!flags[d]) return;                      // block-uniform early exit
  __shared__ int   tgt[T_N];
  __shared__ float wgt[T_N];
  const int tid = threadIdx.x;
  if (tid < T_N) tgt[tid] = dt[d * T_N + tid];
  __syncthreads();
  if (tid < T_N) {
    int v = 1, t = tgt[tid];
    for (int j = 0; j < tid; ++j) v &= (tgt[j] != t);
    wgt[tid] = (float)v;
  }
  __syncthreads();
  const int c0 = tid * 8;
  float aA[8] = {0,0,0,0,0,0,0,0};
  float aB[8] = {0,0,0,0,0,0,0,0};
  #pragma unroll 4
  for (int t = 0; t < T_N; ++t) {
    const float  w   = wgt[t];
    const size_t row = (size_t)tgt[t];
    uint4 a = *(const uint4*)(W1b + row * H1_N + c0);
    uint4 b = *(const uint4*)(W1b + (19001 + row) * H1_N + c0);
    uint32_t au[4] = {a.x, a.y, a.z, a.w};
    uint32_t bu[4] = {b.x, b.y, b.z, b.w};
    #pragma unroll
    for (int k = 0; k < 4; ++k) {
      aA[2*k]   = fmaf(w, bflo(au[k]), aA[2*k]);
      aA[2*k+1] = fmaf(w, bfhi(au[k]), aA[2*k+1]);
      aB[2*k]   = fmaf(w, bflo(bu[k]), aB[2*k]);
      aB[2*k+1] = fmaf(w, bfhi(bu[k]), aB[2*k+1]);
    }
  }
  unsigned short oa[8], ob[8];
  #pragma unroll
  for (int k = 0; k < 8; ++k) { oa[k] = f2bf(aA[k]); ob[k] = f2bf(aB[k]); }
  *(uint4*)(SAb + (size_t)d * H1_N + c0) = *(uint4*)oa;
  *(uint4*)(SBb + (size_t)d * H1_N + c0) = *(uint4*)ob;
}

// K2: h1[r,:] = relu(S_A[dA] + S_B[dB] + cA*W1[P] + cB*W1[2P+1] + b1), bf16 out.
// Rows [0,B): order_1 (dA=drug0). Rows [B,2B): order_2 (dA=drug1).
__global__ __launch_bounds__(256) void k_h1(const int* __restrict__ dp, const float* __restrict__ conc,
                                            const float* __restrict__ W1, const float* __restrict__ b1,
                                            const unsigned short* __restrict__ SAb,
                                            const unsigned short* __restrict__ SBb,
                                            unsigned short* __restrict__ h1) {
  const int rI   = blockIdx.x;
  const int swap = (rI >= B_N) ? 1 : 0;
  const int rr   = swap ? rI - B_N : rI;
  const int dA = dp[2*rr + swap];
  const int dB = dp[2*rr + (1 - swap)];
  const float cA = conc[2*rr + swap];
  const float cB = conc[2*rr + (1 - swap)];
  const int c0 = threadIdx.x * 8;
  uint4 ua = *(const uint4*)(SAb + (size_t)dA * H1_N + c0);
  uint4 ub = *(const uint4*)(SBb + (size_t)dB * H1_N + c0);
  uint32_t au[4] = {ua.x, ua.y, ua.z, ua.w};
  uint32_t bu[4] = {ub.x, ub.y, ub.z, ub.w};
  const float4* wp = (const float4*)(W1 + (size_t)P_N * H1_N + c0);
  const float4* wq = (const float4*)(W1 + (size_t)(2*P_N + 1) * H1_N + c0);
  const float4* bp = (const float4*)(b1 + c0);
  float a[8], b[8], p[8], q[8], z[8];
  #pragma unroll
  for (int k = 0; k < 4; ++k) {
    a[2*k] = bflo(au[k]); a[2*k+1] = bfhi(au[k]);
    b[2*k] = bflo(bu[k]); b[2*k+1] = bfhi(bu[k]);
  }
  float4 p0 = wp[0], p1 = wp[1], q0 = wq[0], q1 = wq[1], z0 = bp[0], z1 = bp[1];
  p[0]=p0.x;p[1]=p0.y;p[2]=p0.z;p[3]=p0.w;p[4]=p1.x;p[5]=p1.y;p[6]=p1.z;p[7]=p1.w;
  q[0]=q0.x;q[1]=q0.y;q[2]=q0.z;q[3]=q0.w;q[4]=q1.x;q[5]=q1.y;q[6]=q1.z;q[7]=q1.w;
  z[0]=z0.x;z[1]=z0.y;z[2]=z0.z;z[3]=z0.w;z[4]=z1.x;z[5]=z1.y;z[6]=z1.z;z[7]=z1.w;
  unsigned short res[8];
  #pragma unroll
  for (int k = 0; k < 8; ++k)
    res[k] = f2bf(fmaxf(a[k] + b[k] + cA*p[k] + cB*q[k] + z[k], 0.f));
  *(uint4*)(h1 + (size_t)rI * H1_N + c0) = *(uint4*)res;
}

// K3: fused h2 = relu(h1 @ W2 + b2), out-partial = sum_col relu(h2)*W3[col].
// BM=64, BN=256, FULL K=2048 per block (ReLU forbids K-splitting).
// Occupancy push: LDS = As 8K + Bs 32K = 40 KB exactly (ps combine removed —
// each wave writes its own partial slot) -> 4 blocks/CU by LDS;
// __launch_bounds__(256,4) caps VGPR at 128 so VGPRs also allow 4 blocks/CU
// (est. K-loop need ~111: 64 acc + 32 frags + addr/temps). More TLP hides the
// per-K-step barrier vmcnt drain (m114). Both-sides XOR slot swizzle (rule 21).
__global__ __launch_bounds__(256, 4) void k_gemm(const unsigned short* __restrict__ A,
                                                 const unsigned short* __restrict__ Bm,
                                                 const float* __restrict__ b2,
                                                 const float* __restrict__ W3,
                                                 float* __restrict__ partial) {
  __shared__ unsigned short As[64 * 64];
  __shared__ unsigned short Bs[256 * 64];
  const int tid  = threadIdx.x;
  const int wv   = tid >> 6;
  const int lane = tid & 63;
  const int bid  = blockIdx.x;
  const int m0 = (bid >> 2) * 64;
  const int nq = bid & 3;                   // n-quarter (256 cols)
  const int n0 = nq * 256;
  const int wn = wv * 64;
  const int r = lane & 15;
  const int g = lane >> 4;
  const int srow = lane >> 3;               // row within 8-row chunk
  const int slot = (lane & 7) ^ srow;       // logical 16B slot this lane fetches

  f32x4 acc[4][4] = {};

  for (int kt = 0; kt < 32; ++kt) {
    const int k0 = kt * 64;
    #pragma unroll
    for (int i = 0; i < 2; ++i) {           // A: 8 chunks of 1KB
      const int c   = i * 4 + wv;
      const int row = c * 8 + srow;
      gload16(A + (size_t)(m0 + row) * H1_N + k0 + slot * 8, (char*)As + c * 1024);
    }
    #pragma unroll
    for (int i = 0; i < 8; ++i) {           // B: 32 chunks of 1KB
      const int c   = i * 4 + wv;
      const int row = c * 8 + srow;
      gload16(Bm + (size_t)(n0 + row) * H1_N + k0 + slot * 8, (char*)Bs + c * 1024);
    }
    __syncthreads();                         // drains vmcnt before compute
    #pragma unroll
    for (int kk = 0; kk < 2; ++kk) {
      bf16x8 af[4], bfr[4];
      #pragma unroll
      for (int mi = 0; mi < 4; ++mi) {
        const int row = mi * 16 + r;
        const int s   = (kk * 4 + g) ^ (row & 7);
        af[mi] = *(const bf16x8*)((const char*)As + row * 128 + s * 16);
      }
      #pragma unroll
      for (int ni = 0; ni < 4; ++ni) {
        const int col = wn + ni * 16 + r;
        const int s   = (kk * 4 + g) ^ (col & 7);
        bfr[ni] = *(const bf16x8*)((const char*)Bs + col * 128 + s * 16);
      }
      #pragma unroll
      for (int mi = 0; mi < 4; ++mi)
        #pragma unroll
        for (int ni = 0; ni < 4; ++ni)
          acc[mi][ni] = __builtin_amdgcn_mfma_f32_16x16x32_bf16(af[mi], bfr[ni], acc[mi][ni], 0, 0, 0);
    }
    __syncthreads();                         // protect LDS before next stage
  }
  // Epilogue: C/D layout col=lane&15 (r), row=g*4+q within fragment.
  // relu+dot with W3 per lane's 4 cols, shfl-reduce the 16-lane col group,
  // then EACH WAVE writes its own partial slot (nq*4+wv) — no LDS combine.
  float b2v[4], w3v[4];
  #pragma unroll
  for (int ni = 0; ni < 4; ++ni) {
    const int col = n0 + wn + ni * 16 + r;
    b2v[ni] = b2[col];
    w3v[ni] = W3[col];
  }
  float rs[16];
  #pragma unroll
  for (int mi = 0; mi < 4; ++mi)
    #pragma unroll
    for (int q = 0; q < 4; ++q) {
      float s = 0.f;
      #pragma unroll
      for (int ni = 0; ni < 4; ++ni)
        s += fmaxf(acc[mi][ni][q] + b2v[ni], 0.f) * w3v[ni];
      rs[mi*4+q] = s;
    }
  #pragma unroll
  for (int o = 1; o < 16; o <<= 1)
    #pragma unroll
    for (int k = 0; k < 16; ++k)
      rs[k] += __shfl_xor(rs[k], o, 64);
  if (r == 0) {
    float* dst = partial + (size_t)(nq * 4 + wv) * (2*B_N) + m0;
    #pragma unroll
    for (int mi = 0; mi < 4; ++mi)
      #pragma unroll
      for (int q = 0; q < 4; ++q)
        dst[mi*16 + g*4 + q] = rs[mi*4+q];
  }
}

// K4: out[i] = sum_{j<16} partial[j][i] + b3
__global__ __launch_bounds__(256) void k_fin(const float* __restrict__ partial,
                                             const float* __restrict__ b3,
                                             float* __restrict__ out) {
  const int i = blockIdx.x * 256 + threadIdx.x;
  float s = b3[0];
  #pragma unroll
  for (int j = 0; j < 16; ++j) s += partial[(size_t)j * (2*B_N) + i];
  out[i] = s;
}

extern "C" void kernel_launch(void* const* d_in, const int* in_sizes, int n_in,
                              void* d_out, int out_size, void* d_ws, size_t ws_size,
                              hipStream_t stream) {
  const int*   dp   = (const int*)d_in[0];
  const int*   dt   = (const int*)d_in[1];
  const float* conc = (const float*)d_in[2];
  const float* W1   = (const float*)d_in[3];
  const float* b1   = (const float*)d_in[4];
  const float* W2   = (const float*)d_in[5];
  const float* b2   = (const float*)d_in[6];
  const float* W3   = (const float*)d_in[7];
  const float* b3   = (const float*)d_in[8];
  float* out = (float*)d_out;

  // ws layout (bytes) — SAb/SBb are 4000*2048*2 = 16,384,000 B each:
  //   [0,         155656192)  W1b bf16 [38002][2048]  (dead after k_dsum)
  //      aliased after k_dsum by:
  //        h1       bf16 [8192][2048] at 0 .. 33554432
  //        partials f32  [16][8192]   at 33554432 .. 34078720
  //   [155656192, 172040192)  SAb bf16 [4000][2048]
  //   [172040192, 188424192)  SBb bf16 [4000][2048]
  //   [188424192, 192618496)  w2t bf16 [1024][2048]
  //   [192618496, 192622496)  flags u8 [4000]          (total ~192.6 MB)
  char* ws = (char*)d_ws;
  unsigned short* W1b   = (unsigned short*)ws;
  unsigned short* h1    = (unsigned short*)ws;
  float*          parts = (float*)(ws + 33554432);
  unsigned short* SAb   = (unsigned short*)(ws + 155656192);
  unsigned short* SBb   = (unsigned short*)(ws + 172040192);
  unsigned short* w2t   = (unsigned short*)(ws + 188424192);
  unsigned char*  flags = (unsigned char*)(ws + 192618496);

  k_prep<<<40051,  256, 0, stream>>>(W1, W1b, W2, w2t, dp, flags);
  k_dsum<<<D_N,    256, 0, stream>>>(dt, flags, W1b, SAb, SBb);
  k_h1  <<<2*B_N,  256, 0, stream>>>(dp, conc, W1, b1, SAb, SBb, h1);
  k_gemm<<<512,    256, 0, stream>>>(h1, w2t, b2, W3, parts);
  k_fin <<<32,     256, 0, stream>>>(parts, b3, out);
}

// Round 10
// 264.919 us; speedup vs baseline: 1.0946x; 1.0219x over previous
//
#include <hip/hip_runtime.h>
#include <stdint.h>

#define B_N  4096
#define P_N  19000
#define D_N  4000
#define T_N  32
#define H1_N 2048
#define H2_N 1024

typedef __bf16 bf16x8 __attribute__((ext_vector_type(8)));
typedef float  f32x4  __attribute__((ext_vector_type(4)));

__device__ __forceinline__ unsigned short f2bf(float f) {
  union { float f; uint32_t u; } v; v.f = f;
  uint32_t u = v.u;
  uint32_t r = (u + 0x7fffu + ((u >> 16) & 1u)) >> 16;  // RNE
  return (unsigned short)r;
}

__device__ __forceinline__ float bflo(uint32_t u) {  // low bf16 of a packed u32
  union { uint32_t u; float f; } v; v.u = u << 16; return v.f;
}
__device__ __forceinline__ float bfhi(uint32_t u) {  // high bf16
  union { uint32_t u; float f; } v; v.u = u & 0xffff0000u; return v.f;
}

__device__ __forceinline__ void gload16(const void* g, void* l) {
  __builtin_amdgcn_global_load_lds((const __attribute__((address_space(1))) void*)g,
                                   (__attribute__((address_space(3))) void*)l,
                                   16, 0, 0);
}

// K0 fused prep: blocks [0,38002) convert W1 f32->bf16 (plain row layout);
// [38002,40050) transpose W2 -> bf16 [N][K]; block 40050 builds used-drug flags.
__global__ __launch_bounds__(256) void k_prep(const float* __restrict__ W1,
                                              unsigned short* __restrict__ W1b,
                                              const float* __restrict__ W2,
                                              unsigned short* __restrict__ W2T,
                                              const int* __restrict__ dp,
                                              unsigned char* __restrict__ flags) {
  __shared__ float tile[32][33];
  const int b = blockIdx.x;
  if (b < 38002) {
    const size_t base = (size_t)b * H1_N + threadIdx.x * 8;
    const float4* p = (const float4*)(W1 + base);
    float4 x = p[0], y = p[1];
    unsigned short r[8] = { f2bf(x.x), f2bf(x.y), f2bf(x.z), f2bf(x.w),
                            f2bf(y.x), f2bf(y.y), f2bf(y.z), f2bf(y.w) };
    *(uint4*)(W1b + base) = *(uint4*)r;
  } else if (b < 38002 + 2048) {
    const int bb = b - 38002;
    const int bx = bb & 31;   // n-tile (1024/32)
    const int by = bb >> 5;   // k-tile (2048/32)
    const int tx = threadIdx.x & 31, ty = threadIdx.x >> 5;
    #pragma unroll
    for (int i = 0; i < 4; ++i)
      tile[ty + i*8][tx] = W2[(size_t)(by*32 + ty + i*8) * H2_N + bx*32 + tx];
    __syncthreads();
    #pragma unroll
    for (int i = 0; i < 4; ++i) {
      const int n = bx*32 + ty + i*8;
      const int k = by*32 + tx;
      W2T[(size_t)n * H1_N + k] = f2bf(tile[tx][ty + i*8]);
    }
  } else {
    const int tid = threadIdx.x;
    for (int i = tid; i < D_N; i += 256) flags[i] = 0;
    __syncthreads();
    for (int i = tid; i < 2 * B_N; i += 256) flags[dp[i]] = 1;
  }
}

// K1: per-drug sums of bf16 W1 rows (dup targets weighted 0; unused drugs skipped).
// Accumulate f32, store bf16. unroll 8: 16 outstanding 16B loads/thread to cover
// the L3 gather latency (L3-resident working set, ~8 TB/s effective path).
__global__ __launch_bounds__(256) void k_dsum(const int* __restrict__ dt,
                                              const unsigned char* __restrict__ flags,
                                              const unsigned short* __restrict__ W1b,
                                              unsigned short* __restrict__ SAb,
                                              unsigned short* __restrict__ SBb) {
  const int d = blockIdx.x;
  if (!flags[d]) return;                      // block-uniform early exit
  __shared__ int   tgt[T_N];
  __shared__ float wgt[T_N];
  const int tid = threadIdx.x;
  if (tid < T_N) tgt[tid] = dt[d * T_N + tid];
  __syncthreads();
  if (tid < T_N) {
    int v = 1, t = tgt[tid];
    for (int j = 0; j < tid; ++j) v &= (tgt[j] != t);
    wgt[tid] = (float)v;
  }
  __syncthreads();
  const int c0 = tid * 8;
  float aA[8] = {0,0,0,0,0,0,0,0};
  float aB[8] = {0,0,0,0,0,0,0,0};
  #pragma unroll 8
  for (int t = 0; t < T_N; ++t) {
    const float  w   = wgt[t];
    const size_t row = (size_t)tgt[t];
    uint4 a = *(const uint4*)(W1b + row * H1_N + c0);
    uint4 b = *(const uint4*)(W1b + (19001 + row) * H1_N + c0);
    uint32_t au[4] = {a.x, a.y, a.z, a.w};
    uint32_t bu[4] = {b.x, b.y, b.z, b.w};
    #pragma unroll
    for (int k = 0; k < 4; ++k) {
      aA[2*k]   = fmaf(w, bflo(au[k]), aA[2*k]);
      aA[2*k+1] = fmaf(w, bfhi(au[k]), aA[2*k+1]);
      aB[2*k]   = fmaf(w, bflo(bu[k]), aB[2*k]);
      aB[2*k+1] = fmaf(w, bfhi(bu[k]), aB[2*k+1]);
    }
  }
  unsigned short oa[8], ob[8];
  #pragma unroll
  for (int k = 0; k < 8; ++k) { oa[k] = f2bf(aA[k]); ob[k] = f2bf(aB[k]); }
  *(uint4*)(SAb + (size_t)d * H1_N + c0) = *(uint4*)oa;
  *(uint4*)(SBb + (size_t)d * H1_N + c0) = *(uint4*)ob;
}

// K2: h1[r,:] = relu(S_A[dA] + S_B[dB] + cA*W1[P] + cB*W1[2P+1] + b1), bf16 out.
// Rows [0,B): order_1 (dA=drug0). Rows [B,2B): order_2 (dA=drug1).
__global__ __launch_bounds__(256) void k_h1(const int* __restrict__ dp, const float* __restrict__ conc,
                                            const float* __restrict__ W1, const float* __restrict__ b1,
                                            const unsigned short* __restrict__ SAb,
                                            const unsigned short* __restrict__ SBb,
                                            unsigned short* __restrict__ h1) {
  const int rI   = blockIdx.x;
  const int swap = (rI >= B_N) ? 1 : 0;
  const int rr   = swap ? rI - B_N : rI;
  const int dA = dp[2*rr + swap];
  const int dB = dp[2*rr + (1 - swap)];
  const float cA = conc[2*rr + swap];
  const float cB = conc[2*rr + (1 - swap)];
  const int c0 = threadIdx.x * 8;
  uint4 ua = *(const uint4*)(SAb + (size_t)dA * H1_N + c0);
  uint4 ub = *(const uint4*)(SBb + (size_t)dB * H1_N + c0);
  uint32_t au[4] = {ua.x, ua.y, ua.z, ua.w};
  uint32_t bu[4] = {ub.x, ub.y, ub.z, ub.w};
  const float4* wp = (const float4*)(W1 + (size_t)P_N * H1_N + c0);
  const float4* wq = (const float4*)(W1 + (size_t)(2*P_N + 1) * H1_N + c0);
  const float4* bp = (const float4*)(b1 + c0);
  float a[8], b[8], p[8], q[8], z[8];
  #pragma unroll
  for (int k = 0; k < 4; ++k) {
    a[2*k] = bflo(au[k]); a[2*k+1] = bfhi(au[k]);
    b[2*k] = bflo(bu[k]); b[2*k+1] = bfhi(bu[k]);
  }
  float4 p0 = wp[0], p1 = wp[1], q0 = wq[0], q1 = wq[1], z0 = bp[0], z1 = bp[1];
  p[0]=p0.x;p[1]=p0.y;p[2]=p0.z;p[3]=p0.w;p[4]=p1.x;p[5]=p1.y;p[6]=p1.z;p[7]=p1.w;
  q[0]=q0.x;q[1]=q0.y;q[2]=q0.z;q[3]=q0.w;q[4]=q1.x;q[5]=q1.y;q[6]=q1.z;q[7]=q1.w;
  z[0]=z0.x;z[1]=z0.y;z[2]=z0.z;z[3]=z0.w;z[4]=z1.x;z[5]=z1.y;z[6]=z1.z;z[7]=z1.w;
  unsigned short res[8];
  #pragma unroll
  for (int k = 0; k < 8; ++k)
    res[k] = f2bf(fmaxf(a[k] + b[k] + cA*p[k] + cB*q[k] + z[k], 0.f));
  *(uint4*)(h1 + (size_t)rI * H1_N + c0) = *(uint4*)res;
}

// K3: fused h2 = relu(h1 @ W2 + b2), out-partial = sum_col relu(h2)*W3[col].
// BM=64, BN=256, FULL K=2048 per block (ReLU forbids K-splitting).
// XCD co-location swizzle: default XCD = blockIdx%8; remap so all 4 nq-siblings
// of an m-tile land on ONE XCD at adjacent dispatch slots -> 256KB A-panel is
// fetched off-XCD once and L2-hit 3x (A fabric traffic 134->34 MB; B 4MB w2t
// stays L2-resident per XCD). LDS = 40KB, launch_bounds(256,4).
// Both-sides XOR slot swizzle (rule 21).
__global__ __launch_bounds__(256, 4) void k_gemm(const unsigned short* __restrict__ A,
                                                 const unsigned short* __restrict__ Bm,
                                                 const float* __restrict__ b2,
                                                 const float* __restrict__ W3,
                                                 float* __restrict__ partial) {
  __shared__ unsigned short As[64 * 64];
  __shared__ unsigned short Bs[256 * 64];
  const int tid  = threadIdx.x;
  const int wv   = tid >> 6;
  const int lane = tid & 63;
  // XCD co-location: x = XCD id, j = slot within XCD (64 slots = 16 m-tiles x 4 nq)
  const int x  = blockIdx.x & 7;
  const int j  = blockIdx.x >> 3;
  const int m0 = (x * 16 + (j >> 2)) * 64;
  const int nq = j & 3;                     // n-quarter (256 cols)
  const int n0 = nq * 256;
  const int wn = wv * 64;
  const int r = lane & 15;
  const int g = lane >> 4;
  const int srow = lane >> 3;               // row within 8-row chunk
  const int slot = (lane & 7) ^ srow;       // logical 16B slot this lane fetches

  f32x4 acc[4][4] = {};

  for (int kt = 0; kt < 32; ++kt) {
    const int k0 = kt * 64;
    #pragma unroll
    for (int i = 0; i < 2; ++i) {           // A: 8 chunks of 1KB
      const int c   = i * 4 + wv;
      const int row = c * 8 + srow;
      gload16(A + (size_t)(m0 + row) * H1_N + k0 + slot * 8, (char*)As + c * 1024);
    }
    #pragma unroll
    for (int i = 0; i < 8; ++i) {           // B: 32 chunks of 1KB
      const int c   = i * 4 + wv;
      const int row = c * 8 + srow;
      gload16(Bm + (size_t)(n0 + row) * H1_N + k0 + slot * 8, (char*)Bs + c * 1024);
    }
    __syncthreads();                         // drains vmcnt before compute
    #pragma unroll
    for (int kk = 0; kk < 2; ++kk) {
      bf16x8 af[4], bfr[4];
      #pragma unroll
      for (int mi = 0; mi < 4; ++mi) {
        const int row = mi * 16 + r;
        const int s   = (kk * 4 + g) ^ (row & 7);
        af[mi] = *(const bf16x8*)((const char*)As + row * 128 + s * 16);
      }
      #pragma unroll
      for (int ni = 0; ni < 4; ++ni) {
        const int col = wn + ni * 16 + r;
        const int s   = (kk * 4 + g) ^ (col & 7);
        bfr[ni] = *(const bf16x8*)((const char*)Bs + col * 128 + s * 16);
      }
      #pragma unroll
      for (int mi = 0; mi < 4; ++mi)
        #pragma unroll
        for (int ni = 0; ni < 4; ++ni)
          acc[mi][ni] = __builtin_amdgcn_mfma_f32_16x16x32_bf16(af[mi], bfr[ni], acc[mi][ni], 0, 0, 0);
    }
    __syncthreads();                         // protect LDS before next stage
  }
  // Epilogue: C/D layout col=lane&15 (r), row=g*4+q within fragment.
  // relu+dot with W3 per lane's 4 cols, shfl-reduce the 16-lane col group,
  // then EACH WAVE writes its own partial slot (nq*4+wv) — no LDS combine.
  float b2v[4], w3v[4];
  #pragma unroll
  for (int ni = 0; ni < 4; ++ni) {
    const int col = n0 + wn + ni * 16 + r;
    b2v[ni] = b2[col];
    w3v[ni] = W3[col];
  }
  float rs[16];
  #pragma unroll
  for (int mi = 0; mi < 4; ++mi)
    #pragma unroll
    for (int q = 0; q < 4; ++q) {
      float s = 0.f;
      #pragma unroll
      for (int ni = 0; ni < 4; ++ni)
        s += fmaxf(acc[mi][ni][q] + b2v[ni], 0.f) * w3v[ni];
      rs[mi*4+q] = s;
    }
  #pragma unroll
  for (int o = 1; o < 16; o <<= 1)
    #pragma unroll
    for (int k = 0; k < 16; ++k)
      rs[k] += __shfl_xor(rs[k], o, 64);
  if (r == 0) {
    float* dst = partial + (size_t)(nq * 4 + wv) * (2*B_N) + m0;
    #pragma unroll
    for (int mi = 0; mi < 4; ++mi)
      #pragma unroll
      for (int q = 0; q < 4; ++q)
        dst[mi*16 + g*4 + q] = rs[mi*4+q];
  }
}

// K4: out[i] = sum_{j<16} partial[j][i] + b3
__global__ __launch_bounds__(256) void k_fin(const float* __restrict__ partial,
                                             const float* __restrict__ b3,
                                             float* __restrict__ out) {
  const int i = blockIdx.x * 256 + threadIdx.x;
  float s = b3[0];
  #pragma unroll
  for (int j = 0; j < 16; ++j) s += partial[(size_t)j * (2*B_N) + i];
  out[i] = s;
}

extern "C" void kernel_launch(void* const* d_in, const int* in_sizes, int n_in,
                              void* d_out, int out_size, void* d_ws, size_t ws_size,
                              hipStream_t stream) {
  const int*   dp   = (const int*)d_in[0];
  const int*   dt   = (const int*)d_in[1];
  const float* conc = (const float*)d_in[2];
  const float* W1   = (const float*)d_in[3];
  const float* b1   = (const float*)d_in[4];
  const float* W2   = (const float*)d_in[5];
  const float* b2   = (const float*)d_in[6];
  const float* W3   = (const float*)d_in[7];
  const float* b3   = (const float*)d_in[8];
  float* out = (float*)d_out;

  // ws layout (bytes) — SAb/SBb are 4000*2048*2 = 16,384,000 B each:
  //   [0,         155656192)  W1b bf16 [38002][2048]  (dead after k_dsum)
  //      aliased after k_dsum by:
  //        h1       bf16 [8192][2048] at 0 .. 33554432
  //        partials f32  [16][8192]   at 33554432 .. 34078720
  //   [155656192, 172040192)  SAb bf16 [4000][2048]
  //   [172040192, 188424192)  SBb bf16 [4000][2048]
  //   [188424192, 192618496)  w2t bf16 [1024][2048]
  //   [192618496, 192622496)  flags u8 [4000]          (total ~192.6 MB)
  char* ws = (char*)d_ws;
  unsigned short* W1b   = (unsigned short*)ws;
  unsigned short* h1    = (unsigned short*)ws;
  float*          parts = (float*)(ws + 33554432);
  unsigned short* SAb   = (unsigned short*)(ws + 155656192);
  unsigned short* SBb   = (unsigned short*)(ws + 172040192);
  unsigned short* w2t   = (unsigned short*)(ws + 188424192);
  unsigned char*  flags = (unsigned char*)(ws + 192618496);

  k_prep<<<40051,  256, 0, stream>>>(W1, W1b, W2, w2t, dp, flags);
  k_dsum<<<D_N,    256, 0, stream>>>(dt, flags, W1b, SAb, SBb);
  k_h1  <<<2*B_N,  256, 0, stream>>>(dp, conc, W1, b1, SAb, SBb, h1);
  k_gemm<<<512,    256, 0, stream>>>(h1, w2t, b2, W3, parts);
  k_fin <<<32,     256, 0, stream>>>(parts, b3, out);
}